// Round 6
// baseline (261.640 us; speedup 1.0000x reference)
//
#include <hip/hip_runtime.h>
#include <math.h>

#define N_PTS 2048
#define M_PTS 128
#define INNF  256
#define H     128

#define MIN_STDC 0.30235680f   /* 0.32*1.88973/2 */
#define MAX_STDC 2.19208680f   /* 2.32*1.88973/2 */
#define PI_F     3.14159265358979f
#define LOG2E_F  1.44269504089f

static __device__ __forceinline__ float silu_f(float x) {
  return x / (1.0f + __expf(-x));
}

// ---------------------------------------------------------------------------
// K1: zero the atomic accumulators (c4, out_pre), then
//     hpre = silu(h @ W_pre + b_pre) and
//     hdg4[n][w][l] = (hpre @ W_down[l])[n,w] * gw[n] * coef(w) / sqrt(2l+1)
// 2 n-rows per block, 256 threads (w = t&127, nh = t>>7 -> one n each).
// 1024 blocks -> 4 waves/SIMD.
// ---------------------------------------------------------------------------
__global__ __launch_bounds__(256) void k_pre(const float* __restrict__ h,
    const float* __restrict__ W_pre, const float* __restrict__ b_pre,
    const float* __restrict__ W_down, const float* __restrict__ gw,
    float* __restrict__ hdg4, float* __restrict__ c4,
    float* __restrict__ out_pre) {
  __shared__ float h_lds[2 * INNF];
  __shared__ float hp_lds[2 * H];
  int t = threadIdx.x;
  int b = blockIdx.x;
  int n0 = b * 2;
  int w  = t & 127;
  int nh = t >> 7;
  int n  = n0 + nh;

  // zero c4 (589824 f = 144 f4/block) and out_pre (262144 f = 64 f4/block)
  const float4 z4 = make_float4(0.f, 0.f, 0.f, 0.f);
  ((float4*)c4)[(size_t)b*144 + t % 144 ] = z4;   // covered twice is fine
  if (t < 144) ((float4*)c4)[(size_t)b*144 + t] = z4;
  if (t < 64)  ((float4*)out_pre)[(size_t)b*64 + t] = z4;

  // stage h rows (512 floats = 128 f4)
  if (t < 128) {
    int row = t >> 6, col = (t & 63) << 2;
    *(float4*)&h_lds[row * INNF + col] =
        *(const float4*)(h + (size_t)(n0 + row) * INNF + col);
  }
  __syncthreads();

  // stage 1: hpre row n (unroll 8 for load ILP)
  float acc = 0.0f;
  for (int u = 0; u < INNF; u += 8) {
    float4 aa = *(const float4*)&h_lds[nh * INNF + u];
    float4 ab = *(const float4*)&h_lds[nh * INNF + u + 4];
    float wv[8];
    #pragma unroll
    for (int i = 0; i < 8; ++i) wv[i] = W_pre[(u + i)*H + w];
    acc += aa.x*wv[0] + aa.y*wv[1] + aa.z*wv[2] + aa.w*wv[3]
         + ab.x*wv[4] + ab.y*wv[5] + ab.z*wv[6] + ab.w*wv[7];
  }
  hp_lds[nh*H + w] = silu_f(acc + b_pre[w]);
  __syncthreads();

  // per-w folded radial coefficient
  const float stp = (MAX_STDC - MIN_STDC) / 127.0f;
  float s = MIN_STDC + (float)w * stp;
  float temps = 2.0f * s * s;
  float coef = (2.0f/3.0f) / (temps * powf(PI_F * temps, 1.5f));
  float gwv = gw[n];
  const float invn1 = 0.57735026919f, invn2 = 0.44721359550f;

  // stage 2: 3 l's for row n
  float a2[3] = {};
  for (int u = 0; u < H; u += 4) {
    float4 p = *(const float4*)&hp_lds[nh*H + u];
    #pragma unroll
    for (int l = 0; l < 3; ++l) {
      float w0 = W_down[((size_t)l*H + u + 0)*H + w];
      float w1 = W_down[((size_t)l*H + u + 1)*H + w];
      float w2 = W_down[((size_t)l*H + u + 2)*H + w];
      float w3 = W_down[((size_t)l*H + u + 3)*H + w];
      a2[l] += p.x*w0 + p.y*w1 + p.z*w2 + p.w*w3;
    }
  }
  float sc = gwv * coef;
  *(float4*)(hdg4 + ((size_t)n * H + w) * 4) =
      make_float4(a2[0]*sc, a2[1]*sc*invn1, a2[2]*sc*invn2, 0.0f);
}

// ---------------------------------------------------------------------------
// K2: pair loop ("down"). SH tile computed in LDS; lane = w; 256 threads
// (nh = t>>7 splits the 64-n chunk), m-tile 4, grid (32 mg, 32 s).
// Results atomically accumulated into c4[ss>>3][m][li][w].
// ---------------------------------------------------------------------------
__global__ __launch_bounds__(256) void k_down(const float* __restrict__ gc,
    const float* __restrict__ cc, const float* __restrict__ hdg4,
    float* __restrict__ c4) {
  __shared__ float lds[4608];   // SH tile 64n*4m*12 = 3072f; reduce reuses 4608f
  int t = threadIdx.x;
  int m0 = blockIdx.x * 4;
  int ss = blockIdx.y;          // 0..31
  int n0 = ss * 64;
  int w  = t & 127;
  int nh = t >> 7;

  // phase 0: each thread computes one (n_loc, m_loc) pair's SH into LDS
  {
    int n_loc = t >> 2, m_loc = t & 3;
    int n = n0 + n_loc, m = m0 + m_loc;
    float dx = gc[3*n]   - cc[3*m];
    float dy = gc[3*n+1] - cc[3*m+1];
    float dz = gc[3*n+2] - cc[3*m+2];
    float d2 = dx*dx + dy*dy + dz*dz + 3e-20f;
    float inv = rsqrtf(d2);
    float x = dx*inv, y = dy*inv, z = dz*inv;
    const float s3 = 1.73205080757f;
    float* dst = &lds[(size_t)t * 12];
    dst[0] = 1.0f; dst[1] = x; dst[2] = y; dst[3] = z;
    dst[4] = s3*x*z; dst[5] = s3*x*y; dst[6] = y*y - 0.5f*(x*x + z*z);
    dst[7] = s3*y*z; dst[8] = 0.5f*s3*(z*z - x*x);
    dst[9] = d2; dst[10] = 0.0f; dst[11] = 0.0f;
  }
  __syncthreads();

  const float stp = (MAX_STDC - MIN_STDC) / 127.0f;
  float sw = MIN_STDC + (float)w * stp;
  float m_nl2t = -LOG2E_F / (2.0f * sw * sw);

  float acc[4][9] = {};
  for (int j = 0; j < 32; j += 4) {
    float4 hv[4];
    #pragma unroll
    for (int q = 0; q < 4; ++q)
      hv[q] = *(const float4*)(hdg4 + ((size_t)(n0 + nh*32 + j + q)*H + w)*4);
    #pragma unroll
    for (int q = 0; q < 4; ++q) {
      const float* shb = &lds[(size_t)(nh*32 + j + q) * 48];
      #pragma unroll
      for (int mm = 0; mm < 4; ++mm) {
        float4 q0 = *(const float4*)(shb + mm*12);
        float4 q1 = *(const float4*)(shb + mm*12 + 4);
        float4 q2 = *(const float4*)(shb + mm*12 + 8);
        float e  = exp2f(q2.y * m_nl2t);
        float rp = e * q2.y;
        float t0 = hv[q].x*rp, t1 = hv[q].y*rp, t2 = hv[q].z*rp;
        acc[mm][0] += t0;
        acc[mm][1] += t1*q0.y; acc[mm][2] += t1*q0.z; acc[mm][3] += t1*q0.w;
        acc[mm][4] += t2*q1.x; acc[mm][5] += t2*q1.y;
        acc[mm][6] += t2*q1.z; acc[mm][7] += t2*q1.w;
        acc[mm][8] += t2*q2.x;
      }
    }
  }

  // cross-nh reduce via LDS, then one atomicAdd per (mm,li)
  __syncthreads();
  if (nh == 1) {
    #pragma unroll
    for (int mm = 0; mm < 4; ++mm)
      #pragma unroll
      for (int li = 0; li < 9; ++li)
        lds[(mm*9 + li)*128 + w] = acc[mm][li];
  }
  __syncthreads();
  if (nh == 0) {
    int s4 = ss >> 3;
    #pragma unroll
    for (int mm = 0; mm < 4; ++mm)
      #pragma unroll
      for (int li = 0; li < 9; ++li) {
        float v = acc[mm][li] + lds[(mm*9 + li)*128 + w];
        atomicAdd(&c4[(((size_t)s4*M_PTS + m0 + mm)*9 + li)*H + w], v);
      }
  }
}

// ---------------------------------------------------------------------------
// K3: per (m, li): sum the 4 c4 partials over u, contract with W_up -> CU9.
// grid (128, 9), 128 threads (w = t).
// ---------------------------------------------------------------------------
__global__ __launch_bounds__(128) void k_cu(const float* __restrict__ c4,
    const float* __restrict__ W_up, float* __restrict__ CU9) {
  __shared__ float c_lds[H];
  int t = threadIdx.x;           // u for stage 1, w for stage 2
  int m = blockIdx.x, li = blockIdx.y;
  size_t base = ((size_t)m*9 + li)*H + t;
  float v = c4[base] + c4[(size_t)1*M_PTS*9*H + base]
          + c4[(size_t)2*M_PTS*9*H + base] + c4[(size_t)3*M_PTS*9*H + base];
  c_lds[t] = v;
  __syncthreads();

  int l = (li == 0) ? 0 : (li < 4 ? 1 : 2);
  const float invn[3] = {1.0f, 0.57735026919f, 0.44721359550f};
  float acc = 0.0f;
  for (int u = 0; u < H; u += 4) {
    float w0 = W_up[((size_t)l*H + u + 0)*H + t];
    float w1 = W_up[((size_t)l*H + u + 1)*H + t];
    float w2 = W_up[((size_t)l*H + u + 2)*H + t];
    float w3 = W_up[((size_t)l*H + u + 3)*H + t];
    acc += c_lds[u]*w0 + c_lds[u+1]*w1 + c_lds[u+2]*w2 + c_lds[u+3]*w3;
  }
  CU9[((size_t)m*9 + li)*H + t] = acc * invn[l];
}

// ---------------------------------------------------------------------------
// K4: up contraction with in-kernel SH recompute, single sync, K=72.
// Block: 32 n x 128 w, 256 threads, thread tile 2n x 8w; ks covers 8 m's.
// grid (64, 16) = 1024 blocks; LDS 46.7 KB -> 3 blocks/CU = 12 waves/CU.
// Accumulates into out_pre via atomicAdd.
// ---------------------------------------------------------------------------
__global__ __launch_bounds__(256) void k_up(const float* __restrict__ gc,
    const float* __restrict__ cc, const float* __restrict__ CU9,
    float* __restrict__ out_pre) {
  __shared__ float At[72 * 34];   // [k][n] pad 34
  __shared__ float Bl[72 * 128];  // [k][w]
  int t = threadIdx.x;
  int n0 = blockIdx.x * 32;
  int ks = blockIdx.y;            // 0..15
  int tgn = t >> 4;               // 0..15 -> n_loc = 2*tgn + r
  int w0 = (t & 15) * 8;

  // stage A: all 256 (n_loc, m_rel) pairs' SH
  {
    int ch = t >> 7, idx = t & 127;
    int n_loc = idx >> 2, m_loc = idx & 3;
    int mrel = ch*4 + m_loc;
    int n = n0 + n_loc, m = ks*8 + mrel;
    float dx = gc[3*n]   - cc[3*m];
    float dy = gc[3*n+1] - cc[3*m+1];
    float dz = gc[3*n+2] - cc[3*m+2];
    float d2 = dx*dx + dy*dy + dz*dz + 3e-20f;
    float inv = rsqrtf(d2);
    float x = dx*inv, y = dy*inv, z = dz*inv;
    const float s3 = 1.73205080757f;
    float sh[9];
    sh[0] = 1.0f; sh[1] = x; sh[2] = y; sh[3] = z;
    sh[4] = s3*x*z; sh[5] = s3*x*y; sh[6] = y*y - 0.5f*(x*x + z*z);
    sh[7] = s3*y*z; sh[8] = 0.5f*s3*(z*z - x*x);
    #pragma unroll
    for (int li = 0; li < 9; ++li)
      At[(mrel*9 + li)*34 + n_loc] = sh[li];
  }
  // stage B: contiguous 72x128 = 2304 f4, 9 per thread
  #pragma unroll
  for (int i = 0; i < 9; ++i) {
    int idx = t + i*256;
    *(float4*)&Bl[idx*4] = *(const float4*)(CU9 + (size_t)ks*72*H + idx*4);
  }
  __syncthreads();

  float acc[2][8] = {};
  #pragma unroll 8
  for (int k = 0; k < 72; ++k) {
    float2 a = *(const float2*)&At[k*34 + 2*tgn];
    float4 b0 = *(const float4*)&Bl[k*128 + w0];
    float4 b1 = *(const float4*)&Bl[k*128 + w0 + 4];
    float bv[8] = {b0.x, b0.y, b0.z, b0.w, b1.x, b1.y, b1.z, b1.w};
    #pragma unroll
    for (int c = 0; c < 8; ++c) {
      acc[0][c] += a.x * bv[c];
      acc[1][c] += a.y * bv[c];
    }
  }
  #pragma unroll
  for (int r = 0; r < 2; ++r) {
    float* dst = out_pre + (size_t)(n0 + 2*tgn + r)*H + w0;
    #pragma unroll
    for (int c = 0; c < 8; ++c)
      atomicAdd(dst + c, acc[r][c]);
  }
}

// ---------------------------------------------------------------------------
// K5: post-MLP (W_post + b_post) + silu -> d_out. 4 n-rows/block, 512 blocks.
// ---------------------------------------------------------------------------
__global__ __launch_bounds__(256) void k_post(const float* __restrict__ out_pre,
    const float* __restrict__ W_post, const float* __restrict__ b_post,
    float* __restrict__ out) {
  __shared__ float op[4 * H];
  int t = threadIdx.x;
  int n0 = blockIdx.x * 4;
  int w = t & 127, nh = t >> 7;

  if (t < 128) {     // stage 4x128 = 128 f4
    int row = t >> 5, col = (t & 31) << 2;
    *(float4*)&op[row*H + col] =
        *(const float4*)(out_pre + (size_t)(n0 + row)*H + col);
  }
  __syncthreads();

  float acc[2] = {0.0f, 0.0f};
  for (int u = 0; u < H; u += 4) {
    float4 p0 = *(const float4*)&op[(nh*2 + 0)*H + u];
    float4 p1 = *(const float4*)&op[(nh*2 + 1)*H + u];
    float w0 = W_post[(u+0)*H + w];
    float w1 = W_post[(u+1)*H + w];
    float w2 = W_post[(u+2)*H + w];
    float w3 = W_post[(u+3)*H + w];
    acc[0] += p0.x*w0 + p0.y*w1 + p0.z*w2 + p0.w*w3;
    acc[1] += p1.x*w0 + p1.y*w1 + p1.z*w2 + p1.w*w3;
  }
  float bp = b_post[w];
  out[(size_t)(n0 + nh*2 + 0)*H + w] = silu_f(acc[0] + bp);
  out[(size_t)(n0 + nh*2 + 1)*H + w] = silu_f(acc[1] + bp);
}

// ---------------------------------------------------------------------------
extern "C" void kernel_launch(void* const* d_in, const int* in_sizes, int n_in,
                              void* d_out, int out_size, void* d_ws, size_t ws_size,
                              hipStream_t stream) {
  const float* h      = (const float*)d_in[0];
  const float* gc     = (const float*)d_in[1];
  const float* cc     = (const float*)d_in[2];
  const float* gw     = (const float*)d_in[3];
  const float* W_pre  = (const float*)d_in[4];
  const float* b_pre  = (const float*)d_in[5];
  const float* W_down = (const float*)d_in[6];
  const float* W_up   = (const float*)d_in[7];
  const float* W_post = (const float*)d_in[8];
  const float* b_post = (const float*)d_in[9];

  float* ws       = (float*)d_ws;
  float* hdg4     = ws;                     // 2048*128*4   = 1,048,576 f
  float* c4       = hdg4 + 1048576;         // 4*128*9*128  =   589,824 f
  float* CU9      = c4 + 589824;            // 128*9*128    =   147,456 f
  float* out_pre  = CU9 + 147456;           // 2048*128     =   262,144 f
  float* out      = (float*)d_out;

  k_pre <<<1024,          256, 0, stream>>>(h, W_pre, b_pre, W_down, gw,
                                            hdg4, c4, out_pre);
  k_down<<<dim3(32,32),   256, 0, stream>>>(gc, cc, hdg4, c4);
  k_cu  <<<dim3(128,9),   128, 0, stream>>>(c4, W_up, CU9);
  k_up  <<<dim3(64,16),   256, 0, stream>>>(gc, cc, CU9, out_pre);
  k_post<<<512,           256, 0, stream>>>(out_pre, W_post, b_post, out);
}

// Round 7
// 155.650 us; speedup vs baseline: 1.6809x; 1.6809x over previous
//
#include <hip/hip_runtime.h>
#include <math.h>

#define N_PTS 2048
#define M_PTS 128
#define INNF  256
#define H     128

#define MIN_STDC 0.30235680f   /* 0.32*1.88973/2 */
#define MAX_STDC 2.19208680f   /* 2.32*1.88973/2 */
#define PI_F     3.14159265358979f
#define LOG2E_F  1.44269504089f

static __device__ __forceinline__ float silu_f(float x) {
  return x / (1.0f + __expf(-x));
}

// ---------------------------------------------------------------------------
// K1: hpre = silu(h @ W_pre + b_pre), then
//     hdg4[n][w][l] = (hpre @ W_down[l])[n,w] * gw[n] * coef(w) / sqrt(2l+1)
// 4 n-rows/block, 512 blocks. Thread = (lw 0..31 -> 4 w's, row 0..3, uh 0..1).
// Weights loaded as float4 (b128) -> 4x fewer VMEM instructions than scalar.
// u-dim split across uh halves, LDS-reduced.
// ---------------------------------------------------------------------------
__global__ __launch_bounds__(256) void k_pre(const float* __restrict__ h,
    const float* __restrict__ W_pre, const float* __restrict__ b_pre,
    const float* __restrict__ W_down, const float* __restrict__ gw,
    float* __restrict__ hdg4) {
  __shared__ float h_lds[4 * INNF];   // 1024 f
  __shared__ float hp_lds[4 * H];     // 512 f
  __shared__ float red[4 * 3 * H];    // 1536 f (stage1 uses first 512)
  int t = threadIdx.x;
  int n0 = blockIdx.x * 4;
  int lw  = t & 31;        // w0 = 4*lw
  int row = (t >> 5) & 3;  // n = n0 + row
  int uh  = t >> 7;        // u-half
  int w0 = lw * 4;
  int n  = n0 + row;

  // stage h rows: 1024 floats = 256 float4, one per thread
  {
    int r4 = t >> 6, c4i = (t & 63) << 2;
    *(float4*)&h_lds[r4 * INNF + c4i] =
        *(const float4*)(h + (size_t)(n0 + r4) * INNF + c4i);
  }
  __syncthreads();

  // ---- stage 1: partial over u-half, 4 w's, 1 row ----
  float a1[4] = {};
  for (int u = uh * 128; u < uh * 128 + 128; u += 2) {
    float hv0 = h_lds[row * INNF + u];
    float hv1 = h_lds[row * INNF + u + 1];
    float4 wv0 = *(const float4*)(W_pre + (size_t)u * H + w0);
    float4 wv1 = *(const float4*)(W_pre + (size_t)(u + 1) * H + w0);
    a1[0] += hv0 * wv0.x + hv1 * wv1.x;
    a1[1] += hv0 * wv0.y + hv1 * wv1.y;
    a1[2] += hv0 * wv0.z + hv1 * wv1.z;
    a1[3] += hv0 * wv0.w + hv1 * wv1.w;
  }
  if (uh == 1) {
    #pragma unroll
    for (int i = 0; i < 4; ++i) red[row * H + w0 + i] = a1[i];
  }
  __syncthreads();
  if (uh == 0) {
    float4 bv = *(const float4*)(b_pre + w0);
    float bb[4] = {bv.x, bv.y, bv.z, bv.w};
    #pragma unroll
    for (int i = 0; i < 4; ++i)
      hp_lds[row * H + w0 + i] = silu_f(a1[i] + red[row * H + w0 + i] + bb[i]);
  }
  __syncthreads();

  // ---- stage 2: partial over u-half, 3 l's x 4 w's, 1 row ----
  float a2[3][4] = {};
  for (int u = uh * 64; u < uh * 64 + 64; ++u) {
    float p = hp_lds[row * H + u];
    #pragma unroll
    for (int l = 0; l < 3; ++l) {
      float4 wv = *(const float4*)(W_down + ((size_t)l * H + u) * H + w0);
      a2[l][0] += p * wv.x; a2[l][1] += p * wv.y;
      a2[l][2] += p * wv.z; a2[l][3] += p * wv.w;
    }
  }
  if (uh == 1) {
    #pragma unroll
    for (int l = 0; l < 3; ++l)
      #pragma unroll
      for (int i = 0; i < 4; ++i)
        red[(row * 3 + l) * H + w0 + i] = a2[l][i];
  }
  __syncthreads();
  if (uh == 0) {
    const float stp = (MAX_STDC - MIN_STDC) / 127.0f;
    const float invn1 = 0.57735026919f, invn2 = 0.44721359550f;
    float gwv = gw[n];
    #pragma unroll
    for (int i = 0; i < 4; ++i) {
      int w = w0 + i;
      float s = MIN_STDC + (float)w * stp;
      float temps = 2.0f * s * s;
      float coef = (2.0f / 3.0f) / (temps * powf(PI_F * temps, 1.5f));
      float sc = gwv * coef;
      float v0 = (a2[0][i] + red[(row * 3 + 0) * H + w]) * sc;
      float v1 = (a2[1][i] + red[(row * 3 + 1) * H + w]) * sc * invn1;
      float v2 = (a2[2][i] + red[(row * 3 + 2) * H + w]) * sc * invn2;
      *(float4*)(hdg4 + ((size_t)n * H + w) * 4) = make_float4(v0, v1, v2, 0.0f);
    }
  }
}

// ---------------------------------------------------------------------------
// K2: pair loop ("down"). SH tile computed in LDS; lane = w; 256 threads
// (nh = t>>7 splits the 64-n chunk), m-tile 4, grid (32 mg, 32 s).
// Plain stores to c_part[s][m][li][w] (NO atomics).
// ---------------------------------------------------------------------------
__global__ __launch_bounds__(256) void k_down(const float* __restrict__ gc,
    const float* __restrict__ cc, const float* __restrict__ hdg4,
    float* __restrict__ c_part) {
  __shared__ float lds[4608];   // SH tile 64n*4m*12 = 3072f; reduce reuses 4608f
  int t = threadIdx.x;
  int m0 = blockIdx.x * 4;
  int ss = blockIdx.y;          // 0..31
  int n0 = ss * 64;
  int w  = t & 127;
  int nh = t >> 7;

  // phase 0: each thread computes one (n_loc, m_loc) pair's SH into LDS
  {
    int n_loc = t >> 2, m_loc = t & 3;
    int n = n0 + n_loc, m = m0 + m_loc;
    float dx = gc[3*n]   - cc[3*m];
    float dy = gc[3*n+1] - cc[3*m+1];
    float dz = gc[3*n+2] - cc[3*m+2];
    float d2 = dx*dx + dy*dy + dz*dz + 3e-20f;
    float inv = rsqrtf(d2);
    float x = dx*inv, y = dy*inv, z = dz*inv;
    const float s3 = 1.73205080757f;
    float* dst = &lds[(size_t)t * 12];
    dst[0] = 1.0f; dst[1] = x; dst[2] = y; dst[3] = z;
    dst[4] = s3*x*z; dst[5] = s3*x*y; dst[6] = y*y - 0.5f*(x*x + z*z);
    dst[7] = s3*y*z; dst[8] = 0.5f*s3*(z*z - x*x);
    dst[9] = d2; dst[10] = 0.0f; dst[11] = 0.0f;
  }
  __syncthreads();

  const float stp = (MAX_STDC - MIN_STDC) / 127.0f;
  float sw = MIN_STDC + (float)w * stp;
  float m_nl2t = -LOG2E_F / (2.0f * sw * sw);

  float acc[4][9] = {};
  for (int j = 0; j < 32; j += 4) {
    float4 hv[4];
    #pragma unroll
    for (int q = 0; q < 4; ++q)
      hv[q] = *(const float4*)(hdg4 + ((size_t)(n0 + nh*32 + j + q)*H + w)*4);
    #pragma unroll
    for (int q = 0; q < 4; ++q) {
      const float* shb = &lds[(size_t)(nh*32 + j + q) * 48];
      #pragma unroll
      for (int mm = 0; mm < 4; ++mm) {
        float4 q0 = *(const float4*)(shb + mm*12);
        float4 q1 = *(const float4*)(shb + mm*12 + 4);
        float4 q2 = *(const float4*)(shb + mm*12 + 8);
        float e  = exp2f(q2.y * m_nl2t);
        float rp = e * q2.y;
        float t0 = hv[q].x*rp, t1 = hv[q].y*rp, t2 = hv[q].z*rp;
        acc[mm][0] += t0;
        acc[mm][1] += t1*q0.y; acc[mm][2] += t1*q0.z; acc[mm][3] += t1*q0.w;
        acc[mm][4] += t2*q1.x; acc[mm][5] += t2*q1.y;
        acc[mm][6] += t2*q1.z; acc[mm][7] += t2*q1.w;
        acc[mm][8] += t2*q2.x;
      }
    }
  }

  // cross-nh reduce via LDS, then plain store
  __syncthreads();
  if (nh == 1) {
    #pragma unroll
    for (int mm = 0; mm < 4; ++mm)
      #pragma unroll
      for (int li = 0; li < 9; ++li)
        lds[(mm*9 + li)*128 + w] = acc[mm][li];
  }
  __syncthreads();
  if (nh == 0) {
    #pragma unroll
    for (int mm = 0; mm < 4; ++mm)
      #pragma unroll
      for (int li = 0; li < 9; ++li) {
        float v = acc[mm][li] + lds[(mm*9 + li)*128 + w];
        c_part[(((size_t)ss*M_PTS + m0 + mm)*9 + li)*H + w] = v;
      }
  }
}

// ---------------------------------------------------------------------------
// K3: block = (m, li): sum 32 s-partials over u into LDS, contract with W_up.
// grid (128, 9) = 1152 blocks, 128 threads.
// ---------------------------------------------------------------------------
__global__ __launch_bounds__(128) void k_cu(const float* __restrict__ c_part,
    const float* __restrict__ W_up, float* __restrict__ CU9) {
  __shared__ float c_lds[H];
  int t = threadIdx.x;           // u in stage 1, w in stage 2
  int m = blockIdx.x, li = blockIdx.y;
  float v = 0.0f;
  #pragma unroll 8
  for (int s = 0; s < 32; ++s)
    v += c_part[(((size_t)s*M_PTS + m)*9 + li)*H + t];
  c_lds[t] = v;
  __syncthreads();

  int l = (li == 0) ? 0 : (li < 4 ? 1 : 2);
  const float invn[3] = {1.0f, 0.57735026919f, 0.44721359550f};
  float acc = 0.0f;
  for (int u = 0; u < H; u += 4) {
    float w0 = W_up[((size_t)l*H + u + 0)*H + t];
    float w1 = W_up[((size_t)l*H + u + 1)*H + t];
    float w2 = W_up[((size_t)l*H + u + 2)*H + t];
    float w3 = W_up[((size_t)l*H + u + 3)*H + t];
    acc += c_lds[u]*w0 + c_lds[u+1]*w1 + c_lds[u+2]*w2 + c_lds[u+3]*w3;
  }
  CU9[((size_t)m*9 + li)*H + t] = acc * invn[l];
}

// ---------------------------------------------------------------------------
// K4: up contraction, in-kernel SH recompute, single barrier, K=72 (8 m's).
// Thread tile 4n x 4w (wq = t&31 -> w0 = 4*wq: conflict-free float4 LDS reads;
// tgn = t>>5 -> n_loc0 = 4*tgn: At reads wave-broadcast).
// grid (64, 16) = 1024 blocks; plain split-K stores to out_part[16].
// ---------------------------------------------------------------------------
__global__ __launch_bounds__(256) void k_up(const float* __restrict__ gc,
    const float* __restrict__ cc, const float* __restrict__ CU9,
    float* __restrict__ out_part) {
  __shared__ float At[72 * 36];   // [mrel*9+li][n_loc], pad 36 keeps f4 alignment
  __shared__ float Bl[72 * 128];  // [k][w]
  int t = threadIdx.x;
  int n0 = blockIdx.x * 32;
  int ks = blockIdx.y;            // 0..15
  int wq  = t & 31;               // w0 = 4*wq
  int tgn = t >> 5;               // n_loc = 4*tgn + r
  int w0 = wq * 4;

  // stage A: all 256 (n_loc, mrel) SH values
  {
    int ch = t >> 7, idx = t & 127;
    int n_loc = idx >> 2, m_loc = idx & 3;
    int mrel = ch*4 + m_loc;
    int n = n0 + n_loc, m = ks*8 + mrel;
    float dx = gc[3*n]   - cc[3*m];
    float dy = gc[3*n+1] - cc[3*m+1];
    float dz = gc[3*n+2] - cc[3*m+2];
    float d2 = dx*dx + dy*dy + dz*dz + 3e-20f;
    float inv = rsqrtf(d2);
    float x = dx*inv, y = dy*inv, z = dz*inv;
    const float s3 = 1.73205080757f;
    float sh[9];
    sh[0] = 1.0f; sh[1] = x; sh[2] = y; sh[3] = z;
    sh[4] = s3*x*z; sh[5] = s3*x*y; sh[6] = y*y - 0.5f*(x*x + z*z);
    sh[7] = s3*y*z; sh[8] = 0.5f*s3*(z*z - x*x);
    #pragma unroll
    for (int li = 0; li < 9; ++li)
      At[(mrel*9 + li)*36 + n_loc] = sh[li];
  }
  // stage B: contiguous 72x128 = 2304 f4, 9 per thread
  #pragma unroll
  for (int i = 0; i < 9; ++i) {
    int idx = t + i*256;
    *(float4*)&Bl[idx*4] = *(const float4*)(CU9 + (size_t)ks*72*H + idx*4);
  }
  __syncthreads();

  float acc[4][4] = {};
  #pragma unroll 8
  for (int k = 0; k < 72; ++k) {
    float4 a = *(const float4*)&At[k*36 + 4*tgn];
    float4 b = *(const float4*)&Bl[k*128 + w0];
    float av[4] = {a.x, a.y, a.z, a.w};
    float bv[4] = {b.x, b.y, b.z, b.w};
    #pragma unroll
    for (int r = 0; r < 4; ++r)
      #pragma unroll
      for (int c = 0; c < 4; ++c)
        acc[r][c] += av[r] * bv[c];
  }
  #pragma unroll
  for (int r = 0; r < 4; ++r) {
    size_t row = (size_t)ks*N_PTS + n0 + 4*tgn + r;
    *(float4*)(out_part + row*H + w0) =
        make_float4(acc[r][0], acc[r][1], acc[r][2], acc[r][3]);
  }
}

// ---------------------------------------------------------------------------
// K5: reduce 16 split-K partials, post-MLP + silu -> d_out.
// ---------------------------------------------------------------------------
__global__ __launch_bounds__(256) void k_post(const float* __restrict__ out_part,
    const float* __restrict__ W_post, const float* __restrict__ b_post,
    float* __restrict__ out) {
  __shared__ float op[4 * H];
  int t = threadIdx.x;
  int n0 = blockIdx.x * 4;
  int w = t & 127, nh = t >> 7;

  #pragma unroll
  for (int i = 0; i < 2; ++i) {
    int idx = t + i*256;                 // 0..511
    int nl = idx >> 7, ww = idx & 127;
    float v = 0.0f;
    #pragma unroll
    for (int s = 0; s < 16; ++s)
      v += out_part[((size_t)s*N_PTS + n0 + nl)*H + ww];
    op[nl*H + ww] = v;
  }
  __syncthreads();

  float acc[2] = {0.0f, 0.0f};
  for (int u = 0; u < H; u += 4) {
    float4 p0 = *(const float4*)&op[(nh*2 + 0)*H + u];
    float4 p1 = *(const float4*)&op[(nh*2 + 1)*H + u];
    float w0 = W_post[(u+0)*H + w];
    float w1 = W_post[(u+1)*H + w];
    float w2 = W_post[(u+2)*H + w];
    float w3 = W_post[(u+3)*H + w];
    acc[0] += p0.x*w0 + p0.y*w1 + p0.z*w2 + p0.w*w3;
    acc[1] += p1.x*w0 + p1.y*w1 + p1.z*w2 + p1.w*w3;
  }
  float bp = b_post[w];
  out[(size_t)(n0 + nh*2 + 0)*H + w] = silu_f(acc[0] + bp);
  out[(size_t)(n0 + nh*2 + 1)*H + w] = silu_f(acc[1] + bp);
}

// ---------------------------------------------------------------------------
extern "C" void kernel_launch(void* const* d_in, const int* in_sizes, int n_in,
                              void* d_out, int out_size, void* d_ws, size_t ws_size,
                              hipStream_t stream) {
  const float* h      = (const float*)d_in[0];
  const float* gc     = (const float*)d_in[1];
  const float* cc     = (const float*)d_in[2];
  const float* gw     = (const float*)d_in[3];
  const float* W_pre  = (const float*)d_in[4];
  const float* b_pre  = (const float*)d_in[5];
  const float* W_down = (const float*)d_in[6];
  const float* W_up   = (const float*)d_in[7];
  const float* W_post = (const float*)d_in[8];
  const float* b_post = (const float*)d_in[9];

  float* ws       = (float*)d_ws;
  float* hdg4     = ws;                     // 2048*128*4   = 1,048,576 f
  float* c_part   = hdg4 + 1048576;         // 32*128*9*128 = 4,718,592 f
  float* CU9      = c_part + 4718592;       // 128*9*128    =   147,456 f
  // out_part (16*2048*128 = 4,194,304 f) aliases c_part (dead after k_cu)
  float* out_part = c_part;
  float* out      = (float*)d_out;

  k_pre <<<512,           256, 0, stream>>>(h, W_pre, b_pre, W_down, gw, hdg4);
  k_down<<<dim3(32,32),   256, 0, stream>>>(gc, cc, hdg4, c_part);
  k_cu  <<<dim3(128,9),   128, 0, stream>>>(c_part, W_up, CU9);
  k_up  <<<dim3(64,16),   256, 0, stream>>>(gc, cc, CU9, out_part);
  k_post<<<512,           256, 0, stream>>>(out_part, W_post, b_post, out);
}

// Round 8
// 147.287 us; speedup vs baseline: 1.7764x; 1.0568x over previous
//
#include <hip/hip_runtime.h>
#include <math.h>

#define N_PTS 2048
#define M_PTS 128
#define INNF  256
#define H     128

#define MIN_STDC 0.30235680f   /* 0.32*1.88973/2 */
#define MAX_STDC 2.19208680f   /* 2.32*1.88973/2 */
#define PI_F     3.14159265358979f
#define LOG2E_F  1.44269504089f

static __device__ __forceinline__ float silu_f(float x) {
  return x / (1.0f + __expf(-x));
}

// ---------------------------------------------------------------------------
// K1 v3: weights staged through LDS (each block reads W_pre/W_down ONCE).
// 256 blocks x 256 thr, 8 n-rows per block.
// Thread = (lw = t&31 -> w0 = 4*lw, g = t>>5 -> n_loc = g).
// stage1: hpre = silu(h @ W_pre + b), K=256 in 4 chunks of 64 rows (32 KB).
// stage2: hdg4 via W_down (3 l's), K=128 in 4 chunks of 32 rows (48 KB).
// All LDS compute reads are b128 (W conflict-free stride-1, h/hp broadcast).
// ---------------------------------------------------------------------------
__global__ __launch_bounds__(256) void k_pre(const float* __restrict__ h,
    const float* __restrict__ W_pre, const float* __restrict__ b_pre,
    const float* __restrict__ W_down, const float* __restrict__ gw,
    float* __restrict__ hdg4) {
  __shared__ float bigW[12288];        // 48 KB: stage1 chunk 64x128, stage2 3x32x128
  __shared__ float h_t[8 * INNF];      // 8 KB [n_loc][u]
  __shared__ float hp_t[8 * H];        // 4 KB [n_loc][u2]
  int t = threadIdx.x;
  int n0 = blockIdx.x * 8;
  int lw = t & 31;                     // w0 = 4*lw
  int g  = t >> 5;                     // n_loc
  int w0 = lw * 4;

  // stage h rows (natural layout): 8x256 = 512 f4, 2 per thread
  #pragma unroll
  for (int i = 0; i < 2; ++i) {
    int idx = t + i * 256;             // 0..511
    int row = idx >> 6, col = (idx & 63) << 2;
    *(float4*)&h_t[row * INNF + col] =
        *(const float4*)(h + (size_t)(n0 + row) * INNF + col);
  }

  // ---- stage 1: K=256 in 4 chunks of 64 ----
  float acc[4] = {};
  for (int kc = 0; kc < 256; kc += 64) {
    __syncthreads();
    #pragma unroll
    for (int i = 0; i < 8; ++i) {      // 64x128 f = 2048 f4, 8 per thread
      int idx = t + i * 256;
      *(float4*)&bigW[idx * 4] = *(const float4*)(W_pre + (size_t)kc * H + idx * 4);
    }
    __syncthreads();
    #pragma unroll 4
    for (int u4 = 0; u4 < 16; ++u4) {  // 4 u's per iter
      float4 hv = *(const float4*)&h_t[g * INNF + kc + u4 * 4];
      float hvv[4] = {hv.x, hv.y, hv.z, hv.w};
      #pragma unroll
      for (int uu = 0; uu < 4; ++uu) {
        float4 wv = *(const float4*)&bigW[(u4 * 4 + uu) * H + w0];
        acc[0] += hvv[uu] * wv.x; acc[1] += hvv[uu] * wv.y;
        acc[2] += hvv[uu] * wv.z; acc[3] += hvv[uu] * wv.w;
      }
    }
  }
  {
    float4 bv = *(const float4*)(b_pre + w0);
    float4 o = make_float4(silu_f(acc[0] + bv.x), silu_f(acc[1] + bv.y),
                           silu_f(acc[2] + bv.z), silu_f(acc[3] + bv.w));
    __syncthreads();                   // bigW rewrite below; also orders hp_t
    *(float4*)&hp_t[g * H + w0] = o;
  }

  // ---- stage 2: K=128 in 4 chunks of 32 (3 l's per chunk) ----
  float acc2[3][4] = {};
  for (int kc = 0; kc < 128; kc += 32) {
    __syncthreads();
    #pragma unroll
    for (int i = 0; i < 12; ++i) {     // 3x32x128 f = 3072 f4, 12 per thread
      int idx = t + i * 256;
      int l = idx >> 10, r4 = idx & 1023;
      *(float4*)&bigW[idx * 4] =
          *(const float4*)(W_down + ((size_t)l * H + kc) * H + r4 * 4);
    }
    __syncthreads();
    #pragma unroll 2
    for (int u4 = 0; u4 < 8; ++u4) {   // 4 u's per iter
      float4 pv = *(const float4*)&hp_t[g * H + kc + u4 * 4];
      float pvv[4] = {pv.x, pv.y, pv.z, pv.w};
      #pragma unroll
      for (int uu = 0; uu < 4; ++uu) {
        int ul = u4 * 4 + uu;
        #pragma unroll
        for (int l = 0; l < 3; ++l) {
          float4 wv = *(const float4*)&bigW[(l * 32 + ul) * H + w0];
          acc2[l][0] += pvv[uu] * wv.x; acc2[l][1] += pvv[uu] * wv.y;
          acc2[l][2] += pvv[uu] * wv.z; acc2[l][3] += pvv[uu] * wv.w;
        }
      }
    }
  }

  // epilogue: fold gw, radial coef, l-norms; write hdg4[n][w][l] f4
  {
    const float stp = (MAX_STDC - MIN_STDC) / 127.0f;
    const float invn1 = 0.57735026919f, invn2 = 0.44721359550f;
    int n = n0 + g;
    float gwv = gw[n];
    #pragma unroll
    for (int i = 0; i < 4; ++i) {
      int w = w0 + i;
      float s = MIN_STDC + (float)w * stp;
      float temps = 2.0f * s * s;
      float coef = (2.0f / 3.0f) / (temps * powf(PI_F * temps, 1.5f));
      float sc = gwv * coef;
      *(float4*)(hdg4 + ((size_t)n * H + w) * 4) =
          make_float4(acc2[0][i] * sc, acc2[1][i] * sc * invn1,
                      acc2[2][i] * sc * invn2, 0.0f);
    }
  }
}

// ---------------------------------------------------------------------------
// K2: pair loop ("down"). SH tile computed in LDS; lane = w; 256 threads
// (nh = t>>7 splits the 64-n chunk), m-tile 4, grid (32 mg, 32 s).
// ---------------------------------------------------------------------------
__global__ __launch_bounds__(256) void k_down(const float* __restrict__ gc,
    const float* __restrict__ cc, const float* __restrict__ hdg4,
    float* __restrict__ c_part) {
  __shared__ float lds[4608];   // SH tile 64n*4m*12 = 3072f; reduce reuses 4608f
  int t = threadIdx.x;
  int m0 = blockIdx.x * 4;
  int ss = blockIdx.y;          // 0..31
  int n0 = ss * 64;
  int w  = t & 127;
  int nh = t >> 7;

  // phase 0: each thread computes one (n_loc, m_loc) pair's SH into LDS
  {
    int n_loc = t >> 2, m_loc = t & 3;
    int n = n0 + n_loc, m = m0 + m_loc;
    float dx = gc[3*n]   - cc[3*m];
    float dy = gc[3*n+1] - cc[3*m+1];
    float dz = gc[3*n+2] - cc[3*m+2];
    float d2 = dx*dx + dy*dy + dz*dz + 3e-20f;
    float inv = rsqrtf(d2);
    float x = dx*inv, y = dy*inv, z = dz*inv;
    const float s3 = 1.73205080757f;
    float* dst = &lds[(size_t)t * 12];
    dst[0] = 1.0f; dst[1] = x; dst[2] = y; dst[3] = z;
    dst[4] = s3*x*z; dst[5] = s3*x*y; dst[6] = y*y - 0.5f*(x*x + z*z);
    dst[7] = s3*y*z; dst[8] = 0.5f*s3*(z*z - x*x);
    dst[9] = d2; dst[10] = 0.0f; dst[11] = 0.0f;
  }
  __syncthreads();

  const float stp = (MAX_STDC - MIN_STDC) / 127.0f;
  float sw = MIN_STDC + (float)w * stp;
  float m_nl2t = -LOG2E_F / (2.0f * sw * sw);

  float acc[4][9] = {};
  for (int j = 0; j < 32; j += 4) {
    float4 hv[4];
    #pragma unroll
    for (int q = 0; q < 4; ++q)
      hv[q] = *(const float4*)(hdg4 + ((size_t)(n0 + nh*32 + j + q)*H + w)*4);
    #pragma unroll
    for (int q = 0; q < 4; ++q) {
      const float* shb = &lds[(size_t)(nh*32 + j + q) * 48];
      #pragma unroll
      for (int mm = 0; mm < 4; ++mm) {
        float4 q0 = *(const float4*)(shb + mm*12);
        float4 q1 = *(const float4*)(shb + mm*12 + 4);
        float4 q2 = *(const float4*)(shb + mm*12 + 8);
        float e  = exp2f(q2.y * m_nl2t);
        float rp = e * q2.y;
        float t0 = hv[q].x*rp, t1 = hv[q].y*rp, t2 = hv[q].z*rp;
        acc[mm][0] += t0;
        acc[mm][1] += t1*q0.y; acc[mm][2] += t1*q0.z; acc[mm][3] += t1*q0.w;
        acc[mm][4] += t2*q1.x; acc[mm][5] += t2*q1.y;
        acc[mm][6] += t2*q1.z; acc[mm][7] += t2*q1.w;
        acc[mm][8] += t2*q2.x;
      }
    }
  }

  // cross-nh reduce via LDS, then plain store
  __syncthreads();
  if (nh == 1) {
    #pragma unroll
    for (int mm = 0; mm < 4; ++mm)
      #pragma unroll
      for (int li = 0; li < 9; ++li)
        lds[(mm*9 + li)*128 + w] = acc[mm][li];
  }
  __syncthreads();
  if (nh == 0) {
    #pragma unroll
    for (int mm = 0; mm < 4; ++mm)
      #pragma unroll
      for (int li = 0; li < 9; ++li) {
        float v = acc[mm][li] + lds[(mm*9 + li)*128 + w];
        c_part[(((size_t)ss*M_PTS + m0 + mm)*9 + li)*H + w] = v;
      }
  }
}

// ---------------------------------------------------------------------------
// K3: block = (m, li): sum 32 s-partials over u into LDS, contract with W_up.
// grid (128, 9) = 1152 blocks, 128 threads.
// ---------------------------------------------------------------------------
__global__ __launch_bounds__(128) void k_cu(const float* __restrict__ c_part,
    const float* __restrict__ W_up, float* __restrict__ CU9) {
  __shared__ float c_lds[H];
  int t = threadIdx.x;           // u in stage 1, w in stage 2
  int m = blockIdx.x, li = blockIdx.y;
  float v = 0.0f;
  #pragma unroll 8
  for (int s = 0; s < 32; ++s)
    v += c_part[(((size_t)s*M_PTS + m)*9 + li)*H + t];
  c_lds[t] = v;
  __syncthreads();

  int l = (li == 0) ? 0 : (li < 4 ? 1 : 2);
  const float invn[3] = {1.0f, 0.57735026919f, 0.44721359550f};
  float acc = 0.0f;
  for (int u = 0; u < H; u += 4) {
    float w0 = W_up[((size_t)l*H + u + 0)*H + t];
    float w1 = W_up[((size_t)l*H + u + 1)*H + t];
    float w2 = W_up[((size_t)l*H + u + 2)*H + t];
    float w3 = W_up[((size_t)l*H + u + 3)*H + t];
    acc += c_lds[u]*w0 + c_lds[u+1]*w1 + c_lds[u+2]*w2 + c_lds[u+3]*w3;
  }
  CU9[((size_t)m*9 + li)*H + t] = acc * invn[l];
}

// ---------------------------------------------------------------------------
// K4: up contraction, in-kernel SH recompute, single barrier, K=72 (8 m's).
// Thread tile 4n x 4w; grid (64, 16); plain split-K stores to out_part[16].
// ---------------------------------------------------------------------------
__global__ __launch_bounds__(256) void k_up(const float* __restrict__ gc,
    const float* __restrict__ cc, const float* __restrict__ CU9,
    float* __restrict__ out_part) {
  __shared__ float At[72 * 36];   // [mrel*9+li][n_loc]
  __shared__ float Bl[72 * 128];  // [k][w]
  int t = threadIdx.x;
  int n0 = blockIdx.x * 32;
  int ks = blockIdx.y;            // 0..15
  int wq  = t & 31;               // w0 = 4*wq
  int tgn = t >> 5;               // n_loc = 4*tgn + r
  int w0 = wq * 4;

  // stage A: all 256 (n_loc, mrel) SH values
  {
    int ch = t >> 7, idx = t & 127;
    int n_loc = idx >> 2, m_loc = idx & 3;
    int mrel = ch*4 + m_loc;
    int n = n0 + n_loc, m = ks*8 + mrel;
    float dx = gc[3*n]   - cc[3*m];
    float dy = gc[3*n+1] - cc[3*m+1];
    float dz = gc[3*n+2] - cc[3*m+2];
    float d2 = dx*dx + dy*dy + dz*dz + 3e-20f;
    float inv = rsqrtf(d2);
    float x = dx*inv, y = dy*inv, z = dz*inv;
    const float s3 = 1.73205080757f;
    float sh[9];
    sh[0] = 1.0f; sh[1] = x; sh[2] = y; sh[3] = z;
    sh[4] = s3*x*z; sh[5] = s3*x*y; sh[6] = y*y - 0.5f*(x*x + z*z);
    sh[7] = s3*y*z; sh[8] = 0.5f*s3*(z*z - x*x);
    #pragma unroll
    for (int li = 0; li < 9; ++li)
      At[(mrel*9 + li)*36 + n_loc] = sh[li];
  }
  // stage B: contiguous 72x128 = 2304 f4, 9 per thread
  #pragma unroll
  for (int i = 0; i < 9; ++i) {
    int idx = t + i*256;
    *(float4*)&Bl[idx*4] = *(const float4*)(CU9 + (size_t)ks*72*H + idx*4);
  }
  __syncthreads();

  float acc[4][4] = {};
  #pragma unroll 8
  for (int k = 0; k < 72; ++k) {
    float4 a = *(const float4*)&At[k*36 + 4*tgn];
    float4 b = *(const float4*)&Bl[k*128 + w0];
    float av[4] = {a.x, a.y, a.z, a.w};
    float bv[4] = {b.x, b.y, b.z, b.w};
    #pragma unroll
    for (int r = 0; r < 4; ++r)
      #pragma unroll
      for (int c = 0; c < 4; ++c)
        acc[r][c] += av[r] * bv[c];
  }
  #pragma unroll
  for (int r = 0; r < 4; ++r) {
    size_t row = (size_t)ks*N_PTS + n0 + 4*tgn + r;
    *(float4*)(out_part + row*H + w0) =
        make_float4(acc[r][0], acc[r][1], acc[r][2], acc[r][3]);
  }
}

// ---------------------------------------------------------------------------
// K5: reduce 16 split-K partials, post-MLP + silu -> d_out.
// ---------------------------------------------------------------------------
__global__ __launch_bounds__(256) void k_post(const float* __restrict__ out_part,
    const float* __restrict__ W_post, const float* __restrict__ b_post,
    float* __restrict__ out) {
  __shared__ float op[4 * H];
  int t = threadIdx.x;
  int n0 = blockIdx.x * 4;
  int w = t & 127, nh = t >> 7;

  #pragma unroll
  for (int i = 0; i < 2; ++i) {
    int idx = t + i*256;                 // 0..511
    int nl = idx >> 7, ww = idx & 127;
    float v = 0.0f;
    #pragma unroll
    for (int s = 0; s < 16; ++s)
      v += out_part[((size_t)s*N_PTS + n0 + nl)*H + ww];
    op[nl*H + ww] = v;
  }
  __syncthreads();

  float acc[2] = {0.0f, 0.0f};
  for (int u = 0; u < H; u += 4) {
    float4 p0 = *(const float4*)&op[(nh*2 + 0)*H + u];
    float4 p1 = *(const float4*)&op[(nh*2 + 1)*H + u];
    float w0 = W_post[(u+0)*H + w];
    float w1 = W_post[(u+1)*H + w];
    float w2 = W_post[(u+2)*H + w];
    float w3 = W_post[(u+3)*H + w];
    acc[0] += p0.x*w0 + p0.y*w1 + p0.z*w2 + p0.w*w3;
    acc[1] += p1.x*w0 + p1.y*w1 + p1.z*w2 + p1.w*w3;
  }
  float bp = b_post[w];
  out[(size_t)(n0 + nh*2 + 0)*H + w] = silu_f(acc[0] + bp);
  out[(size_t)(n0 + nh*2 + 1)*H + w] = silu_f(acc[1] + bp);
}

// ---------------------------------------------------------------------------
extern "C" void kernel_launch(void* const* d_in, const int* in_sizes, int n_in,
                              void* d_out, int out_size, void* d_ws, size_t ws_size,
                              hipStream_t stream) {
  const float* h      = (const float*)d_in[0];
  const float* gc     = (const float*)d_in[1];
  const float* cc     = (const float*)d_in[2];
  const float* gw     = (const float*)d_in[3];
  const float* W_pre  = (const float*)d_in[4];
  const float* b_pre  = (const float*)d_in[5];
  const float* W_down = (const float*)d_in[6];
  const float* W_up   = (const float*)d_in[7];
  const float* W_post = (const float*)d_in[8];
  const float* b_post = (const float*)d_in[9];

  float* ws       = (float*)d_ws;
  float* hdg4     = ws;                     // 2048*128*4   = 1,048,576 f
  float* c_part   = hdg4 + 1048576;         // 32*128*9*128 = 4,718,592 f
  float* CU9      = c_part + 4718592;       // 128*9*128    =   147,456 f
  // out_part (16*2048*128 = 4,194,304 f) aliases c_part (dead after k_cu)
  float* out_part = c_part;
  float* out      = (float*)d_out;

  k_pre <<<256,           256, 0, stream>>>(h, W_pre, b_pre, W_down, gw, hdg4);
  k_down<<<dim3(32,32),   256, 0, stream>>>(gc, cc, hdg4, c_part);
  k_cu  <<<dim3(128,9),   128, 0, stream>>>(c_part, W_up, CU9);
  k_up  <<<dim3(64,16),   256, 0, stream>>>(gc, cc, CU9, out_part);
  k_post<<<512,           256, 0, stream>>>(out_part, W_post, b_post, out);
}

// Round 9
// 145.778 us; speedup vs baseline: 1.7948x; 1.0103x over previous
//
#include <hip/hip_runtime.h>
#include <math.h>

#define N_PTS 2048
#define M_PTS 128
#define INNF  256
#define H     128

#define MIN_STDC 0.30235680f   /* 0.32*1.88973/2 */
#define MAX_STDC 2.19208680f   /* 2.32*1.88973/2 */
#define PI_F     3.14159265358979f
#define LOG2E_F  1.44269504089f

static __device__ __forceinline__ float silu_f(float x) {
  return x / (1.0f + __expf(-x));
}

// ---------------------------------------------------------------------------
// K1 v3 (unchanged from R8): weights staged through LDS once per block.
// ---------------------------------------------------------------------------
__global__ __launch_bounds__(256) void k_pre(const float* __restrict__ h,
    const float* __restrict__ W_pre, const float* __restrict__ b_pre,
    const float* __restrict__ W_down, const float* __restrict__ gw,
    float* __restrict__ hdg4) {
  __shared__ float bigW[12288];
  __shared__ float h_t[8 * INNF];
  __shared__ float hp_t[8 * H];
  int t = threadIdx.x;
  int n0 = blockIdx.x * 8;
  int lw = t & 31;
  int g  = t >> 5;
  int w0 = lw * 4;

  #pragma unroll
  for (int i = 0; i < 2; ++i) {
    int idx = t + i * 256;
    int row = idx >> 6, col = (idx & 63) << 2;
    *(float4*)&h_t[row * INNF + col] =
        *(const float4*)(h + (size_t)(n0 + row) * INNF + col);
  }

  float acc[4] = {};
  for (int kc = 0; kc < 256; kc += 64) {
    __syncthreads();
    #pragma unroll
    for (int i = 0; i < 8; ++i) {
      int idx = t + i * 256;
      *(float4*)&bigW[idx * 4] = *(const float4*)(W_pre + (size_t)kc * H + idx * 4);
    }
    __syncthreads();
    #pragma unroll 4
    for (int u4 = 0; u4 < 16; ++u4) {
      float4 hv = *(const float4*)&h_t[g * INNF + kc + u4 * 4];
      float hvv[4] = {hv.x, hv.y, hv.z, hv.w};
      #pragma unroll
      for (int uu = 0; uu < 4; ++uu) {
        float4 wv = *(const float4*)&bigW[(u4 * 4 + uu) * H + w0];
        acc[0] += hvv[uu] * wv.x; acc[1] += hvv[uu] * wv.y;
        acc[2] += hvv[uu] * wv.z; acc[3] += hvv[uu] * wv.w;
      }
    }
  }
  {
    float4 bv = *(const float4*)(b_pre + w0);
    float4 o = make_float4(silu_f(acc[0] + bv.x), silu_f(acc[1] + bv.y),
                           silu_f(acc[2] + bv.z), silu_f(acc[3] + bv.w));
    __syncthreads();
    *(float4*)&hp_t[g * H + w0] = o;
  }

  float acc2[3][4] = {};
  for (int kc = 0; kc < 128; kc += 32) {
    __syncthreads();
    #pragma unroll
    for (int i = 0; i < 12; ++i) {
      int idx = t + i * 256;
      int l = idx >> 10, r4 = idx & 1023;
      *(float4*)&bigW[idx * 4] =
          *(const float4*)(W_down + ((size_t)l * H + kc) * H + r4 * 4);
    }
    __syncthreads();
    #pragma unroll 2
    for (int u4 = 0; u4 < 8; ++u4) {
      float4 pv = *(const float4*)&hp_t[g * H + kc + u4 * 4];
      float pvv[4] = {pv.x, pv.y, pv.z, pv.w};
      #pragma unroll
      for (int uu = 0; uu < 4; ++uu) {
        int ul = u4 * 4 + uu;
        #pragma unroll
        for (int l = 0; l < 3; ++l) {
          float4 wv = *(const float4*)&bigW[(l * 32 + ul) * H + w0];
          acc2[l][0] += pvv[uu] * wv.x; acc2[l][1] += pvv[uu] * wv.y;
          acc2[l][2] += pvv[uu] * wv.z; acc2[l][3] += pvv[uu] * wv.w;
        }
      }
    }
  }

  {
    const float stp = (MAX_STDC - MIN_STDC) / 127.0f;
    const float invn1 = 0.57735026919f, invn2 = 0.44721359550f;
    int n = n0 + g;
    float gwv = gw[n];
    #pragma unroll
    for (int i = 0; i < 4; ++i) {
      int w = w0 + i;
      float s = MIN_STDC + (float)w * stp;
      float temps = 2.0f * s * s;
      float coef = (2.0f / 3.0f) / (temps * powf(PI_F * temps, 1.5f));
      float sc = gwv * coef;
      *(float4*)(hdg4 + ((size_t)n * H + w) * 4) =
          make_float4(acc2[0][i] * sc, acc2[1][i] * sc * invn1,
                      acc2[2][i] * sc * invn2, 0.0f);
    }
  }
}

// ---------------------------------------------------------------------------
// K2 v3: pair loop, 2 w per lane -> each (n,m) visited by ONE wave (halves
// LDS broadcast-read issue). 4 waves each own a private 16-n subchunk;
// 2-stage LDS tree reduce at the end. grid (32 mg, 32 s) = 1024 blocks.
// ---------------------------------------------------------------------------
__global__ __launch_bounds__(256) void k_down(const float* __restrict__ gc,
    const float* __restrict__ cc, const float* __restrict__ hdg4,
    float* __restrict__ c_part) {
  __shared__ float sh_t[3072];    // [n_loc][m_loc][12]
  __shared__ float red[9216];     // 2 x 4608 tree-reduce buffers
  int t = threadIdx.x;
  int m0 = blockIdx.x * 4;
  int ss = blockIdx.y;            // 0..31
  int n0 = ss * 64;
  int wv = t >> 6;                // wave 0..3
  int ln = t & 63;
  int w0 = ln * 2;                // 2 w's per lane

  // phase 0: SH tile (64n x 4m), one pair per thread
  {
    int n_loc = t >> 2, m_loc = t & 3;
    int n = n0 + n_loc, m = m0 + m_loc;
    float dx = gc[3*n]   - cc[3*m];
    float dy = gc[3*n+1] - cc[3*m+1];
    float dz = gc[3*n+2] - cc[3*m+2];
    float d2 = dx*dx + dy*dy + dz*dz + 3e-20f;
    float inv = rsqrtf(d2);
    float x = dx*inv, y = dy*inv, z = dz*inv;
    const float s3 = 1.73205080757f;
    float* dst = &sh_t[(size_t)t * 12];
    dst[0] = 1.0f; dst[1] = x; dst[2] = y; dst[3] = z;
    dst[4] = s3*x*z; dst[5] = s3*x*y; dst[6] = y*y - 0.5f*(x*x + z*z);
    dst[7] = s3*y*z; dst[8] = 0.5f*s3*(z*z - x*x);
    dst[9] = d2; dst[10] = 0.0f; dst[11] = 0.0f;
  }
  __syncthreads();

  const float stp = (MAX_STDC - MIN_STDC) / 127.0f;
  float sA = MIN_STDC + (float)w0 * stp;
  float sB = MIN_STDC + (float)(w0 + 1) * stp;
  float cA = -LOG2E_F / (2.0f * sA * sA);
  float cB = -LOG2E_F / (2.0f * sB * sB);

  float acc[4][9][2] = {};
  for (int j = 0; j < 16; ++j) {
    int nl = wv * 16 + j;
    const float4* hb = (const float4*)(hdg4 + ((size_t)(n0 + nl) * H + w0) * 4);
    float4 hv0 = hb[0];
    float4 hv1 = hb[1];
    const float* shb = &sh_t[(size_t)nl * 48];
    #pragma unroll
    for (int mm = 0; mm < 4; ++mm) {
      float4 q0 = *(const float4*)(shb + mm*12);
      float4 q1 = *(const float4*)(shb + mm*12 + 4);
      float4 q2 = *(const float4*)(shb + mm*12 + 8);
      float e0 = exp2f(q2.y * cA);
      float e1 = exp2f(q2.y * cB);
      float rp0 = e0 * q2.y, rp1 = e1 * q2.y;
      float a00 = hv0.x*rp0, a01 = hv0.y*rp0, a02 = hv0.z*rp0;
      float a10 = hv1.x*rp1, a11 = hv1.y*rp1, a12 = hv1.z*rp1;
      acc[mm][0][0] += a00;        acc[mm][0][1] += a10;
      acc[mm][1][0] += a01*q0.y;   acc[mm][1][1] += a11*q0.y;
      acc[mm][2][0] += a01*q0.z;   acc[mm][2][1] += a11*q0.z;
      acc[mm][3][0] += a01*q0.w;   acc[mm][3][1] += a11*q0.w;
      acc[mm][4][0] += a02*q1.x;   acc[mm][4][1] += a12*q1.x;
      acc[mm][5][0] += a02*q1.y;   acc[mm][5][1] += a12*q1.y;
      acc[mm][6][0] += a02*q1.z;   acc[mm][6][1] += a12*q1.z;
      acc[mm][7][0] += a02*q1.w;   acc[mm][7][1] += a12*q1.w;
      acc[mm][8][0] += a02*q2.x;   acc[mm][8][1] += a12*q2.x;
    }
  }

  // tree reduce: waves 1,3 -> LDS; 0,2 add; wave 2 -> LDS; 0 adds + stores
  __syncthreads();
  if (wv & 1) {
    float* dst = &red[(wv >> 1) * 4608];
    #pragma unroll
    for (int mm = 0; mm < 4; ++mm)
      #pragma unroll
      for (int li = 0; li < 9; ++li)
        *(float2*)&dst[(mm*9 + li)*128 + w0] =
            make_float2(acc[mm][li][0], acc[mm][li][1]);
  }
  __syncthreads();
  if (!(wv & 1)) {
    const float* src = &red[(wv >> 1) * 4608];
    #pragma unroll
    for (int mm = 0; mm < 4; ++mm)
      #pragma unroll
      for (int li = 0; li < 9; ++li) {
        float2 v = *(const float2*)&src[(mm*9 + li)*128 + w0];
        acc[mm][li][0] += v.x; acc[mm][li][1] += v.y;
      }
  }
  __syncthreads();
  if (wv == 2) {
    #pragma unroll
    for (int mm = 0; mm < 4; ++mm)
      #pragma unroll
      for (int li = 0; li < 9; ++li)
        *(float2*)&red[(mm*9 + li)*128 + w0] =
            make_float2(acc[mm][li][0], acc[mm][li][1]);
  }
  __syncthreads();
  if (wv == 0) {
    #pragma unroll
    for (int mm = 0; mm < 4; ++mm)
      #pragma unroll
      for (int li = 0; li < 9; ++li) {
        float2 v = *(const float2*)&red[(mm*9 + li)*128 + w0];
        float2 o = make_float2(acc[mm][li][0] + v.x, acc[mm][li][1] + v.y);
        *(float2*)&c_part[(((size_t)ss*M_PTS + m0 + mm)*9 + li)*H + w0] = o;
      }
  }
}

// ---------------------------------------------------------------------------
// K3: block = (m, li): sum 32 s-partials over u into LDS, contract with W_up.
// grid (128, 9) = 1152 blocks, 128 threads.
// ---------------------------------------------------------------------------
__global__ __launch_bounds__(128) void k_cu(const float* __restrict__ c_part,
    const float* __restrict__ W_up, float* __restrict__ CU9) {
  __shared__ float c_lds[H];
  int t = threadIdx.x;
  int m = blockIdx.x, li = blockIdx.y;
  float v = 0.0f;
  #pragma unroll 8
  for (int s = 0; s < 32; ++s)
    v += c_part[(((size_t)s*M_PTS + m)*9 + li)*H + t];
  c_lds[t] = v;
  __syncthreads();

  int l = (li == 0) ? 0 : (li < 4 ? 1 : 2);
  const float invn[3] = {1.0f, 0.57735026919f, 0.44721359550f};
  float acc = 0.0f;
  for (int u = 0; u < H; u += 4) {
    float w0 = W_up[((size_t)l*H + u + 0)*H + t];
    float w1 = W_up[((size_t)l*H + u + 1)*H + t];
    float w2 = W_up[((size_t)l*H + u + 2)*H + t];
    float w3 = W_up[((size_t)l*H + u + 3)*H + t];
    acc += c_lds[u]*w0 + c_lds[u+1]*w1 + c_lds[u+2]*w2 + c_lds[u+3]*w3;
  }
  CU9[((size_t)m*9 + li)*H + t] = acc * invn[l];
}

// ---------------------------------------------------------------------------
// K4 v2: up contraction, thread tile 4n x 8w (32 FMA per 3 LDS reads).
// Block tile 64n x 128w, grid (32, 16) = 512 blocks, 2 blocks/CU.
// K=72 (8 m's), in-kernel SH, single barrier, split-K stores.
// ---------------------------------------------------------------------------
__global__ __launch_bounds__(256) void k_up(const float* __restrict__ gc,
    const float* __restrict__ cc, const float* __restrict__ CU9,
    float* __restrict__ out_part) {
  __shared__ float At[72 * 68];   // [mrel*9+li][n_loc], pad 68
  __shared__ float Bl[72 * 128];  // [k][w]
  int t = threadIdx.x;
  int n0 = blockIdx.x * 64;
  int ks = blockIdx.y;            // 0..15
  int wq  = t & 15;               // w0 = 8*wq
  int tgn = t >> 4;               // 0..15, n_loc0 = 4*tgn
  int w0 = wq * 8;

  // stage A: 64n x 8m = 512 SH pairs, 2 per thread
  #pragma unroll
  for (int i = 0; i < 2; ++i) {
    int idx = t + i * 256;        // 0..511
    int n_loc = idx >> 3, mrel = idx & 7;
    int n = n0 + n_loc, m = ks*8 + mrel;
    float dx = gc[3*n]   - cc[3*m];
    float dy = gc[3*n+1] - cc[3*m+1];
    float dz = gc[3*n+2] - cc[3*m+2];
    float d2 = dx*dx + dy*dy + dz*dz + 3e-20f;
    float inv = rsqrtf(d2);
    float x = dx*inv, y = dy*inv, z = dz*inv;
    const float s3 = 1.73205080757f;
    float sh[9];
    sh[0] = 1.0f; sh[1] = x; sh[2] = y; sh[3] = z;
    sh[4] = s3*x*z; sh[5] = s3*x*y; sh[6] = y*y - 0.5f*(x*x + z*z);
    sh[7] = s3*y*z; sh[8] = 0.5f*s3*(z*z - x*x);
    #pragma unroll
    for (int li = 0; li < 9; ++li)
      At[(mrel*9 + li)*68 + n_loc] = sh[li];
  }
  // stage B: 72x128 = 2304 f4, 9 per thread
  #pragma unroll
  for (int i = 0; i < 9; ++i) {
    int idx = t + i*256;
    *(float4*)&Bl[idx*4] = *(const float4*)(CU9 + (size_t)ks*72*H + idx*4);
  }
  __syncthreads();

  float acc[4][8] = {};
  #pragma unroll 8
  for (int k = 0; k < 72; ++k) {
    float4 a  = *(const float4*)&At[k*68 + 4*tgn];
    float4 b0 = *(const float4*)&Bl[k*128 + w0];
    float4 b1 = *(const float4*)&Bl[k*128 + w0 + 4];
    float av[4] = {a.x, a.y, a.z, a.w};
    float bv[8] = {b0.x, b0.y, b0.z, b0.w, b1.x, b1.y, b1.z, b1.w};
    #pragma unroll
    for (int r = 0; r < 4; ++r)
      #pragma unroll
      for (int c = 0; c < 8; ++c)
        acc[r][c] += av[r] * bv[c];
  }
  #pragma unroll
  for (int r = 0; r < 4; ++r) {
    size_t row = (size_t)ks*N_PTS + n0 + 4*tgn + r;
    *(float4*)(out_part + row*H + w0) =
        make_float4(acc[r][0], acc[r][1], acc[r][2], acc[r][3]);
    *(float4*)(out_part + row*H + w0 + 4) =
        make_float4(acc[r][4], acc[r][5], acc[r][6], acc[r][7]);
  }
}

// ---------------------------------------------------------------------------
// K5: reduce 16 split-K partials, post-MLP + silu -> d_out.
// ---------------------------------------------------------------------------
__global__ __launch_bounds__(256) void k_post(const float* __restrict__ out_part,
    const float* __restrict__ W_post, const float* __restrict__ b_post,
    float* __restrict__ out) {
  __shared__ float op[4 * H];
  int t = threadIdx.x;
  int n0 = blockIdx.x * 4;
  int w = t & 127, nh = t >> 7;

  #pragma unroll
  for (int i = 0; i < 2; ++i) {
    int idx = t + i*256;
    int nl = idx >> 7, ww = idx & 127;
    float v = 0.0f;
    #pragma unroll
    for (int s = 0; s < 16; ++s)
      v += out_part[((size_t)s*N_PTS + n0 + nl)*H + ww];
    op[nl*H + ww] = v;
  }
  __syncthreads();

  float acc[2] = {0.0f, 0.0f};
  for (int u = 0; u < H; u += 4) {
    float4 p0 = *(const float4*)&op[(nh*2 + 0)*H + u];
    float4 p1 = *(const float4*)&op[(nh*2 + 1)*H + u];
    float w0 = W_post[(u+0)*H + w];
    float w1 = W_post[(u+1)*H + w];
    float w2 = W_post[(u+2)*H + w];
    float w3 = W_post[(u+3)*H + w];
    acc[0] += p0.x*w0 + p0.y*w1 + p0.z*w2 + p0.w*w3;
    acc[1] += p1.x*w0 + p1.y*w1 + p1.z*w2 + p1.w*w3;
  }
  float bp = b_post[w];
  out[(size_t)(n0 + nh*2 + 0)*H + w] = silu_f(acc[0] + bp);
  out[(size_t)(n0 + nh*2 + 1)*H + w] = silu_f(acc[1] + bp);
}

// ---------------------------------------------------------------------------
extern "C" void kernel_launch(void* const* d_in, const int* in_sizes, int n_in,
                              void* d_out, int out_size, void* d_ws, size_t ws_size,
                              hipStream_t stream) {
  const float* h      = (const float*)d_in[0];
  const float* gc     = (const float*)d_in[1];
  const float* cc     = (const float*)d_in[2];
  const float* gw     = (const float*)d_in[3];
  const float* W_pre  = (const float*)d_in[4];
  const float* b_pre  = (const float*)d_in[5];
  const float* W_down = (const float*)d_in[6];
  const float* W_up   = (const float*)d_in[7];
  const float* W_post = (const float*)d_in[8];
  const float* b_post = (const float*)d_in[9];

  float* ws       = (float*)d_ws;
  float* hdg4     = ws;                     // 2048*128*4   = 1,048,576 f
  float* c_part   = hdg4 + 1048576;         // 32*128*9*128 = 4,718,592 f
  float* CU9      = c_part + 4718592;       // 128*9*128    =   147,456 f
  float* out_part = c_part;                 // aliases c_part (dead after k_cu)
  float* out      = (float*)d_out;

  k_pre <<<256,           256, 0, stream>>>(h, W_pre, b_pre, W_down, gw, hdg4);
  k_down<<<dim3(32,32),   256, 0, stream>>>(gc, cc, hdg4, c_part);
  k_cu  <<<dim3(128,9),   128, 0, stream>>>(c_part, W_up, CU9);
  k_up  <<<dim3(32,16),   256, 0, stream>>>(gc, cc, CU9, out_part);
  k_post<<<512,           256, 0, stream>>>(out_part, W_post, b_post, out);
}

// Round 10
// 142.520 us; speedup vs baseline: 1.8358x; 1.0229x over previous
//
#include <hip/hip_runtime.h>
#include <math.h>

#define N_PTS 2048
#define M_PTS 128
#define INNF  256
#define H     128

#define MIN_STDC 0.30235680f   /* 0.32*1.88973/2 */
#define MAX_STDC 2.19208680f   /* 2.32*1.88973/2 */
#define PI_F     3.14159265358979f
#define LOG2E_F  1.44269504089f

static __device__ __forceinline__ float silu_f(float x) {
  return x / (1.0f + __expf(-x));
}

// ---------------------------------------------------------------------------
// K1 (unchanged): weights staged through LDS once per block. 256 blocks.
// ---------------------------------------------------------------------------
__global__ __launch_bounds__(256) void k_pre(const float* __restrict__ h,
    const float* __restrict__ W_pre, const float* __restrict__ b_pre,
    const float* __restrict__ W_down, const float* __restrict__ gw,
    float* __restrict__ hdg4) {
  __shared__ float bigW[12288];
  __shared__ float h_t[8 * INNF];
  __shared__ float hp_t[8 * H];
  int t = threadIdx.x;
  int n0 = blockIdx.x * 8;
  int lw = t & 31;
  int g  = t >> 5;
  int w0 = lw * 4;

  #pragma unroll
  for (int i = 0; i < 2; ++i) {
    int idx = t + i * 256;
    int row = idx >> 6, col = (idx & 63) << 2;
    *(float4*)&h_t[row * INNF + col] =
        *(const float4*)(h + (size_t)(n0 + row) * INNF + col);
  }

  float acc[4] = {};
  for (int kc = 0; kc < 256; kc += 64) {
    __syncthreads();
    #pragma unroll
    for (int i = 0; i < 8; ++i) {
      int idx = t + i * 256;
      *(float4*)&bigW[idx * 4] = *(const float4*)(W_pre + (size_t)kc * H + idx * 4);
    }
    __syncthreads();
    #pragma unroll 4
    for (int u4 = 0; u4 < 16; ++u4) {
      float4 hv = *(const float4*)&h_t[g * INNF + kc + u4 * 4];
      float hvv[4] = {hv.x, hv.y, hv.z, hv.w};
      #pragma unroll
      for (int uu = 0; uu < 4; ++uu) {
        float4 wv = *(const float4*)&bigW[(u4 * 4 + uu) * H + w0];
        acc[0] += hvv[uu] * wv.x; acc[1] += hvv[uu] * wv.y;
        acc[2] += hvv[uu] * wv.z; acc[3] += hvv[uu] * wv.w;
      }
    }
  }
  {
    float4 bv = *(const float4*)(b_pre + w0);
    float4 o = make_float4(silu_f(acc[0] + bv.x), silu_f(acc[1] + bv.y),
                           silu_f(acc[2] + bv.z), silu_f(acc[3] + bv.w));
    __syncthreads();
    *(float4*)&hp_t[g * H + w0] = o;
  }

  float acc2[3][4] = {};
  for (int kc = 0; kc < 128; kc += 32) {
    __syncthreads();
    #pragma unroll
    for (int i = 0; i < 12; ++i) {
      int idx = t + i * 256;
      int l = idx >> 10, r4 = idx & 1023;
      *(float4*)&bigW[idx * 4] =
          *(const float4*)(W_down + ((size_t)l * H + kc) * H + r4 * 4);
    }
    __syncthreads();
    #pragma unroll 2
    for (int u4 = 0; u4 < 8; ++u4) {
      float4 pv = *(const float4*)&hp_t[g * H + kc + u4 * 4];
      float pvv[4] = {pv.x, pv.y, pv.z, pv.w};
      #pragma unroll
      for (int uu = 0; uu < 4; ++uu) {
        int ul = u4 * 4 + uu;
        #pragma unroll
        for (int l = 0; l < 3; ++l) {
          float4 wv = *(const float4*)&bigW[(l * 32 + ul) * H + w0];
          acc2[l][0] += pvv[uu] * wv.x; acc2[l][1] += pvv[uu] * wv.y;
          acc2[l][2] += pvv[uu] * wv.z; acc2[l][3] += pvv[uu] * wv.w;
        }
      }
    }
  }

  {
    const float stp = (MAX_STDC - MIN_STDC) / 127.0f;
    const float invn1 = 0.57735026919f, invn2 = 0.44721359550f;
    int n = n0 + g;
    float gwv = gw[n];
    #pragma unroll
    for (int i = 0; i < 4; ++i) {
      int w = w0 + i;
      float s = MIN_STDC + (float)w * stp;
      float temps = 2.0f * s * s;
      float coef = (2.0f / 3.0f) / (temps * powf(PI_F * temps, 1.5f));
      float sc = gwv * coef;
      *(float4*)(hdg4 + ((size_t)n * H + w) * 4) =
          make_float4(acc2[0][i] * sc, acc2[1][i] * sc * invn1,
                      acc2[2][i] * sc * invn2, 0.0f);
    }
  }
}

// ---------------------------------------------------------------------------
// K2 (unchanged from R9): pair loop, 2 w per lane, private 16-n subchunks,
// 2-stage LDS tree reduce. grid (32 mg, 32 s) = 1024 blocks.
// ---------------------------------------------------------------------------
__global__ __launch_bounds__(256) void k_down(const float* __restrict__ gc,
    const float* __restrict__ cc, const float* __restrict__ hdg4,
    float* __restrict__ c_part) {
  __shared__ float sh_t[3072];
  __shared__ float red[9216];
  int t = threadIdx.x;
  int m0 = blockIdx.x * 4;
  int ss = blockIdx.y;
  int n0 = ss * 64;
  int wv = t >> 6;
  int ln = t & 63;
  int w0 = ln * 2;

  {
    int n_loc = t >> 2, m_loc = t & 3;
    int n = n0 + n_loc, m = m0 + m_loc;
    float dx = gc[3*n]   - cc[3*m];
    float dy = gc[3*n+1] - cc[3*m+1];
    float dz = gc[3*n+2] - cc[3*m+2];
    float d2 = dx*dx + dy*dy + dz*dz + 3e-20f;
    float inv = rsqrtf(d2);
    float x = dx*inv, y = dy*inv, z = dz*inv;
    const float s3 = 1.73205080757f;
    float* dst = &sh_t[(size_t)t * 12];
    dst[0] = 1.0f; dst[1] = x; dst[2] = y; dst[3] = z;
    dst[4] = s3*x*z; dst[5] = s3*x*y; dst[6] = y*y - 0.5f*(x*x + z*z);
    dst[7] = s3*y*z; dst[8] = 0.5f*s3*(z*z - x*x);
    dst[9] = d2; dst[10] = 0.0f; dst[11] = 0.0f;
  }
  __syncthreads();

  const float stp = (MAX_STDC - MIN_STDC) / 127.0f;
  float sA = MIN_STDC + (float)w0 * stp;
  float sB = MIN_STDC + (float)(w0 + 1) * stp;
  float cA = -LOG2E_F / (2.0f * sA * sA);
  float cB = -LOG2E_F / (2.0f * sB * sB);

  float acc[4][9][2] = {};
  for (int j = 0; j < 16; ++j) {
    int nl = wv * 16 + j;
    const float4* hb = (const float4*)(hdg4 + ((size_t)(n0 + nl) * H + w0) * 4);
    float4 hv0 = hb[0];
    float4 hv1 = hb[1];
    const float* shb = &sh_t[(size_t)nl * 48];
    #pragma unroll
    for (int mm = 0; mm < 4; ++mm) {
      float4 q0 = *(const float4*)(shb + mm*12);
      float4 q1 = *(const float4*)(shb + mm*12 + 4);
      float4 q2 = *(const float4*)(shb + mm*12 + 8);
      float e0 = exp2f(q2.y * cA);
      float e1 = exp2f(q2.y * cB);
      float rp0 = e0 * q2.y, rp1 = e1 * q2.y;
      float a00 = hv0.x*rp0, a01 = hv0.y*rp0, a02 = hv0.z*rp0;
      float a10 = hv1.x*rp1, a11 = hv1.y*rp1, a12 = hv1.z*rp1;
      acc[mm][0][0] += a00;        acc[mm][0][1] += a10;
      acc[mm][1][0] += a01*q0.y;   acc[mm][1][1] += a11*q0.y;
      acc[mm][2][0] += a01*q0.z;   acc[mm][2][1] += a11*q0.z;
      acc[mm][3][0] += a01*q0.w;   acc[mm][3][1] += a11*q0.w;
      acc[mm][4][0] += a02*q1.x;   acc[mm][4][1] += a12*q1.x;
      acc[mm][5][0] += a02*q1.y;   acc[mm][5][1] += a12*q1.y;
      acc[mm][6][0] += a02*q1.z;   acc[mm][6][1] += a12*q1.z;
      acc[mm][7][0] += a02*q1.w;   acc[mm][7][1] += a12*q1.w;
      acc[mm][8][0] += a02*q2.x;   acc[mm][8][1] += a12*q2.x;
    }
  }

  __syncthreads();
  if (wv & 1) {
    float* dst = &red[(wv >> 1) * 4608];
    #pragma unroll
    for (int mm = 0; mm < 4; ++mm)
      #pragma unroll
      for (int li = 0; li < 9; ++li)
        *(float2*)&dst[(mm*9 + li)*128 + w0] =
            make_float2(acc[mm][li][0], acc[mm][li][1]);
  }
  __syncthreads();
  if (!(wv & 1)) {
    const float* src = &red[(wv >> 1) * 4608];
    #pragma unroll
    for (int mm = 0; mm < 4; ++mm)
      #pragma unroll
      for (int li = 0; li < 9; ++li) {
        float2 v = *(const float2*)&src[(mm*9 + li)*128 + w0];
        acc[mm][li][0] += v.x; acc[mm][li][1] += v.y;
      }
  }
  __syncthreads();
  if (wv == 2) {
    #pragma unroll
    for (int mm = 0; mm < 4; ++mm)
      #pragma unroll
      for (int li = 0; li < 9; ++li)
        *(float2*)&red[(mm*9 + li)*128 + w0] =
            make_float2(acc[mm][li][0], acc[mm][li][1]);
  }
  __syncthreads();
  if (wv == 0) {
    #pragma unroll
    for (int mm = 0; mm < 4; ++mm)
      #pragma unroll
      for (int li = 0; li < 9; ++li) {
        float2 v = *(const float2*)&red[(mm*9 + li)*128 + w0];
        float2 o = make_float2(acc[mm][li][0] + v.x, acc[mm][li][1] + v.y);
        *(float2*)&c_part[(((size_t)ss*M_PTS + m0 + mm)*9 + li)*H + w0] = o;
      }
  }
}

// ---------------------------------------------------------------------------
// K3 (unchanged): block = (m, li), grid (128, 9) = 1152 blocks, 128 threads.
// ---------------------------------------------------------------------------
__global__ __launch_bounds__(128) void k_cu(const float* __restrict__ c_part,
    const float* __restrict__ W_up, float* __restrict__ CU9) {
  __shared__ float c_lds[H];
  int t = threadIdx.x;
  int m = blockIdx.x, li = blockIdx.y;
  float v = 0.0f;
  #pragma unroll 8
  for (int s = 0; s < 32; ++s)
    v += c_part[(((size_t)s*M_PTS + m)*9 + li)*H + t];
  c_lds[t] = v;
  __syncthreads();

  int l = (li == 0) ? 0 : (li < 4 ? 1 : 2);
  const float invn[3] = {1.0f, 0.57735026919f, 0.44721359550f};
  float acc = 0.0f;
  for (int u = 0; u < H; u += 4) {
    float w0 = W_up[((size_t)l*H + u + 0)*H + t];
    float w1 = W_up[((size_t)l*H + u + 1)*H + t];
    float w2 = W_up[((size_t)l*H + u + 2)*H + t];
    float w3 = W_up[((size_t)l*H + u + 3)*H + t];
    acc += c_lds[u]*w0 + c_lds[u+1]*w1 + c_lds[u+2]*w2 + c_lds[u+3]*w3;
  }
  CU9[((size_t)m*9 + li)*H + t] = acc * invn[l];
}

// ---------------------------------------------------------------------------
// K4 v3: split-K 8 (16 m's per block, two 72-K chunks). Block tile 32n x 128w,
// thread tile 4n x 4w; grid (64, 8) = 512 blocks (2/CU, 8 waves/CU).
// LDS ~47 KB. Halves out_part traffic vs split-K 16.
// ---------------------------------------------------------------------------
__global__ __launch_bounds__(256) void k_up(const float* __restrict__ gc,
    const float* __restrict__ cc, const float* __restrict__ CU9,
    float* __restrict__ out_part) {
  __shared__ float At[72 * 36];   // [mrel*9+li][n_loc 0..31]
  __shared__ float Bl[72 * 128];  // [k][w]
  int t = threadIdx.x;
  int n0 = blockIdx.x * 32;
  int ks = blockIdx.y;            // 0..7
  int wq  = t & 31;               // w0 = 4*wq
  int tgn = t >> 5;               // 0..7, n_loc0 = 4*tgn
  int w0 = wq * 4;
  float acc[4][4] = {};

  for (int ch = 0; ch < 2; ++ch) {
    int m0 = ks*16 + ch*8;
    if (ch) __syncthreads();      // previous chunk's readers done
    // stage A: 32n x 8m = 256 SH pairs, one per thread
    {
      int n_loc = t >> 3, mrel = t & 7;
      int n = n0 + n_loc, m = m0 + mrel;
      float dx = gc[3*n]   - cc[3*m];
      float dy = gc[3*n+1] - cc[3*m+1];
      float dz = gc[3*n+2] - cc[3*m+2];
      float d2 = dx*dx + dy*dy + dz*dz + 3e-20f;
      float inv = rsqrtf(d2);
      float x = dx*inv, y = dy*inv, z = dz*inv;
      const float s3 = 1.73205080757f;
      float sh[9];
      sh[0] = 1.0f; sh[1] = x; sh[2] = y; sh[3] = z;
      sh[4] = s3*x*z; sh[5] = s3*x*y; sh[6] = y*y - 0.5f*(x*x + z*z);
      sh[7] = s3*y*z; sh[8] = 0.5f*s3*(z*z - x*x);
      #pragma unroll
      for (int li = 0; li < 9; ++li)
        At[(mrel*9 + li)*36 + n_loc] = sh[li];
    }
    // stage B: 72x128 = 2304 f4, 9 per thread
    #pragma unroll
    for (int i = 0; i < 9; ++i) {
      int idx = t + i*256;
      *(float4*)&Bl[idx*4] = *(const float4*)(CU9 + (size_t)m0*9*H + idx*4);
    }
    __syncthreads();

    #pragma unroll 8
    for (int k = 0; k < 72; ++k) {
      float4 a = *(const float4*)&At[k*36 + 4*tgn];
      float4 b = *(const float4*)&Bl[k*128 + w0];
      float av[4] = {a.x, a.y, a.z, a.w};
      float bv[4] = {b.x, b.y, b.z, b.w};
      #pragma unroll
      for (int r = 0; r < 4; ++r)
        #pragma unroll
        for (int c = 0; c < 4; ++c)
          acc[r][c] += av[r] * bv[c];
    }
  }
  #pragma unroll
  for (int r = 0; r < 4; ++r) {
    size_t row = (size_t)ks*N_PTS + n0 + 4*tgn + r;
    *(float4*)(out_part + row*H + w0) =
        make_float4(acc[r][0], acc[r][1], acc[r][2], acc[r][3]);
  }
}

// ---------------------------------------------------------------------------
// K5: reduce 8 split-K partials, post-MLP + silu -> d_out.
// ---------------------------------------------------------------------------
__global__ __launch_bounds__(256) void k_post(const float* __restrict__ out_part,
    const float* __restrict__ W_post, const float* __restrict__ b_post,
    float* __restrict__ out) {
  __shared__ float op[4 * H];
  int t = threadIdx.x;
  int n0 = blockIdx.x * 4;
  int w = t & 127, nh = t >> 7;

  #pragma unroll
  for (int i = 0; i < 2; ++i) {
    int idx = t + i*256;
    int nl = idx >> 7, ww = idx & 127;
    float v = 0.0f;
    #pragma unroll
    for (int s = 0; s < 8; ++s)
      v += out_part[((size_t)s*N_PTS + n0 + nl)*H + ww];
    op[nl*H + ww] = v;
  }
  __syncthreads();

  float acc[2] = {0.0f, 0.0f};
  for (int u = 0; u < H; u += 4) {
    float4 p0 = *(const float4*)&op[(nh*2 + 0)*H + u];
    float4 p1 = *(const float4*)&op[(nh*2 + 1)*H + u];
    float w0 = W_post[(u+0)*H + w];
    float w1 = W_post[(u+1)*H + w];
    float w2 = W_post[(u+2)*H + w];
    float w3 = W_post[(u+3)*H + w];
    acc[0] += p0.x*w0 + p0.y*w1 + p0.z*w2 + p0.w*w3;
    acc[1] += p1.x*w0 + p1.y*w1 + p1.z*w2 + p1.w*w3;
  }
  float bp = b_post[w];
  out[(size_t)(n0 + nh*2 + 0)*H + w] = silu_f(acc[0] + bp);
  out[(size_t)(n0 + nh*2 + 1)*H + w] = silu_f(acc[1] + bp);
}

// ---------------------------------------------------------------------------
extern "C" void kernel_launch(void* const* d_in, const int* in_sizes, int n_in,
                              void* d_out, int out_size, void* d_ws, size_t ws_size,
                              hipStream_t stream) {
  const float* h      = (const float*)d_in[0];
  const float* gc     = (const float*)d_in[1];
  const float* cc     = (const float*)d_in[2];
  const float* gw     = (const float*)d_in[3];
  const float* W_pre  = (const float*)d_in[4];
  const float* b_pre  = (const float*)d_in[5];
  const float* W_down = (const float*)d_in[6];
  const float* W_up   = (const float*)d_in[7];
  const float* W_post = (const float*)d_in[8];
  const float* b_post = (const float*)d_in[9];

  float* ws       = (float*)d_ws;
  float* hdg4     = ws;                     // 2048*128*4   = 1,048,576 f
  float* c_part   = hdg4 + 1048576;         // 32*128*9*128 = 4,718,592 f
  float* CU9      = c_part + 4718592;       // 128*9*128    =   147,456 f
  float* out_part = c_part;                 // 8*2048*128 aliases c_part
  float* out      = (float*)d_out;

  k_pre <<<256,           256, 0, stream>>>(h, W_pre, b_pre, W_down, gw, hdg4);
  k_down<<<dim3(32,32),   256, 0, stream>>>(gc, cc, hdg4, c_part);
  k_cu  <<<dim3(128,9),   128, 0, stream>>>(c_part, W_up, CU9);
  k_up  <<<dim3(64,8),    256, 0, stream>>>(gc, cc, CU9, out_part);
  k_post<<<512,           256, 0, stream>>>(out_part, W_post, b_post, out);
}